// Round 10
// baseline (7921.342 us; speedup 1.0000x reference)
//
#include <hip/hip_runtime.h>
#include <math.h>

// Problem constants
#define KK     128
#define HH     384
#define H3     1152
#define PP     200
#define LL     50
#define VV     512
#define BB     256
#define II     16
#define NSTEPS 3

#define KP     129    // keys LDS pitch (f32)
#define NT     576    // 9 waves; 2*NT == H3
#define NW     9      // waves per block

#define GH_G   24     // k-groups of 16 for w_hh (384/16)
#define PPAD   208
#define GI_G   13     // k-groups of 16 for w_ih (208/16)

// fp8 pack, (group, wave, lane) slab layout:
// uint4 index u4 = (g*NW + w)*128 + s*64 + l   (s=0: row j0=2*tid, s=1: j0+1)
// uint m of u4 covers k = 16g + 4m .. +3
#define WGH_U  (GH_G * NW * 128 * 4)   // 110592 uints (442 KB)
#define WGI_U  (GI_G * NW * 128 * 4)   // 59904  uints (240 KB)

typedef float floatx2 __attribute__((ext_vector_type(2)));

__device__ __forceinline__ floatx2 cvt_lo(unsigned u) {
    return __builtin_amdgcn_cvt_pk_f32_fp8(u, false);   // bytes 0,1
}
__device__ __forceinline__ floatx2 cvt_hi(unsigned u) {
    return __builtin_amdgcn_cvt_pk_f32_fp8(u, true);    // bytes 2,3
}
__device__ __forceinline__ float rcpf(float x) { return __builtin_amdgcn_rcpf(x); }
__device__ __forceinline__ float sigm(float x) { return rcpf(1.f + __expf(-x)); }
__device__ __forceinline__ float tanh_fast(float x) {
    float xc = fminf(fmaxf(x, -15.f), 15.f);
    float t = __expf(2.f * xc);
    return 1.f - 2.f * rcpf(t + 1.f);
}
__device__ __forceinline__ void wait_vm4() { asm volatile("s_waitcnt vmcnt(4)" ::: "memory"); }
__device__ __forceinline__ void wait_vm2() { asm volatile("s_waitcnt vmcnt(2)" ::: "memory"); }
__device__ __forceinline__ void wait_vm0() { asm volatile("s_waitcnt vmcnt(0)" ::: "memory"); }

// fp8 weight pack into slab layout (see above)
__global__ void pack_weights(const float* __restrict__ w_hh,
                             const float* __restrict__ w_ih,
                             unsigned* __restrict__ ws)
{
    int idx = blockIdx.x * 256 + threadIdx.x;
    if (idx < WGH_U) {
        int u4 = idx >> 2, m = idx & 3;
        int g = u4 / (NW * 128);
        int off = u4 - g * (NW * 128);
        int w = off >> 7;
        int o = off & 127;
        int s = o >> 6, l = o & 63;
        int j = 2 * (w * 64 + l) + s;
        int k = 16 * g + 4 * m;
        const float* wr = w_hh + (long)j * HH + k;
        int p = __builtin_amdgcn_cvt_pk_fp8_f32(wr[0], wr[1], 0, false);
        p     = __builtin_amdgcn_cvt_pk_fp8_f32(wr[2], wr[3], p, true);
        ws[idx] = (unsigned)p;
    } else if (idx < WGH_U + WGI_U) {
        int q = idx - WGH_U;
        int u4 = q >> 2, m = q & 3;
        int g = u4 / (NW * 128);
        int off = u4 - g * (NW * 128);
        int w = off >> 7;
        int o = off & 127;
        int s = o >> 6, l = o & 63;
        int j = 2 * (w * 64 + l) + s;
        int k = 16 * g + 4 * m;
        float w0 = (k + 0 < PP) ? w_ih[(long)j * PP + k + 0] : 0.f;
        float w1 = (k + 1 < PP) ? w_ih[(long)j * PP + k + 1] : 0.f;
        float w2 = (k + 2 < PP) ? w_ih[(long)j * PP + k + 2] : 0.f;
        float w3 = (k + 3 < PP) ? w_ih[(long)j * PP + k + 3] : 0.f;
        int p = __builtin_amdgcn_cvt_pk_fp8_f32(w0, w1, 0, false);
        p     = __builtin_amdgcn_cvt_pk_fp8_f32(w2, w3, p, true);
        ws[idx] = (unsigned)p;
    }
}

struct __align__(16) Smem {
    unsigned wbuf[NW * 4 * 512];   // 72 KB: per-wave 4-slot ring (2 KB slots)
    float h[HH];
    float prog[PPAD];
    float keys[LL * KP];
    float gi[H3];
    float gh[H3];
    float ra[LL], wmm[LL], rl[LL], wl[LL], rowoff[LL];
    float partial[8 * LL];
};  // ~111 KB

// issue one pair (A,B) of 1KB global_load_lds for k-group g
__device__ __forceinline__ void gld_pair(const char* gwave, unsigned* lwb, int g) {
    const int slot = g & 3;
    const char* src = gwave + (size_t)g * (NW * 2048);
    __builtin_amdgcn_global_load_lds((const unsigned*)(src),        lwb + slot * 512,       16, 0, 0);
    __builtin_amdgcn_global_load_lds((const unsigned*)(src + 1024), lwb + slot * 512 + 256, 16, 0, 0);
}

// 16-k fp8 dual-row dot, float2 lanes (v_pk_fma-friendly)
__device__ __forceinline__ void dot16(uint4 wa, uint4 wb, const floatx2* h2,
                                      floatx2& a0, floatx2& a1) {
    a0 += cvt_lo(wa.x) * h2[0]; a0 += cvt_hi(wa.x) * h2[1];
    a0 += cvt_lo(wa.y) * h2[2]; a0 += cvt_hi(wa.y) * h2[3];
    a0 += cvt_lo(wa.z) * h2[4]; a0 += cvt_hi(wa.z) * h2[5];
    a0 += cvt_lo(wa.w) * h2[6]; a0 += cvt_hi(wa.w) * h2[7];
    a1 += cvt_lo(wb.x) * h2[0]; a1 += cvt_hi(wb.x) * h2[1];
    a1 += cvt_lo(wb.y) * h2[2]; a1 += cvt_hi(wb.y) * h2[3];
    a1 += cvt_lo(wb.z) * h2[4]; a1 += cvt_hi(wb.z) * h2[5];
    a1 += cvt_lo(wb.w) * h2[6]; a1 += cvt_hi(wb.w) * h2[7];
}

__global__ __launch_bounds__(NT)
void symop_main(const int* __restrict__ instr,
                const float* __restrict__ gate_emb,
                const float* __restrict__ program_emb,
                const float* __restrict__ primitive_emb,
                const unsigned* __restrict__ wgh,
                const unsigned* __restrict__ wgi,
                const float* __restrict__ b_ih,
                const float* __restrict__ b_hh,
                const float* __restrict__ keys_g,
                const float* __restrict__ init_value,
                float* __restrict__ out)
{
    __shared__ Smem sm;

    const int tid  = threadIdx.x;
    const int lane = tid & 63;
    const int wid  = tid >> 6;
    const int b    = blockIdx.x;

    // init
    for (int idx = tid; idx < LL * KK; idx += NT) {
        int l = idx >> 7, k = idx & 127;
        sm.keys[l * KP + k] = keys_g[idx];
    }
    float hcur = 0.f;
    if (tid < HH) {
        hcur = keys_g[tid & 127];
        sm.h[tid] = hcur;
    }
    float vreg[LL];
    if (tid < VV) {
        const float iv = init_value[tid];
        #pragma unroll
        for (int l = 0; l < LL; ++l) vreg[l] = iv;
    }
    __syncthreads();

    const int j0 = 2 * tid;
    const float2 bh2 = *(const float2*)(b_hh + j0);
    const float2 bi2 = *(const float2*)(b_ih + j0);

    unsigned* lwb = sm.wbuf + (size_t)wid * 2048;                     // wave's ring (uints)
    const char* gw_hh = (const char*)wgh + (size_t)wid * 2048 + (size_t)lane * 16;
    const char* gw_ih = (const char*)wgi + (size_t)wid * 2048 + (size_t)lane * 16;

    for (int i = 0; i < II; ++i) {
        const int word = instr[i * BB + b];
        const float ge0 = gate_emb[2 * word], ge1 = gate_emb[2 * word + 1];
        const float gmx = fmaxf(ge0, ge1);
        const float e0 = __expf(ge0 - gmx), e1 = __expf(ge1 - gmx);
        const float g0 = e0 * rcpf(e0 + e1), g1 = 1.0f - g0;
        const float primv = (tid < VV) ? primitive_emb[(long)word * VV + tid] : 0.f;
        const float* pge = program_emb + (long)word * PP;

        if (tid < PPAD) sm.prog[tid] = (tid < PP) ? pge[tid] : 0.f;

        // gi prologue (weights independent of prog; overlap with staging barrier)
        gld_pair(gw_ih, lwb, 0);
        gld_pair(gw_ih, lwb, 1);
        gld_pair(gw_ih, lwb, 2);
        __syncthreads();

        // gi = W_ih @ prog + b_ih  — fp8 stream via per-wave LDS ring
        {
            floatx2 a0 = {bi2.x, 0.f}, a1 = {bi2.y, 0.f};
            #pragma unroll
            for (int g = 0; g < GI_G; ++g) {
                if (g <= GI_G - 3)      wait_vm4();
                else if (g == GI_G - 2) wait_vm2();
                else                    wait_vm0();
                const int slot = g & 3;
                uint4 wa = *(const uint4*)(lwb + slot * 512 + lane * 4);
                uint4 wb = *(const uint4*)(lwb + slot * 512 + 256 + lane * 4);
                dot16(wa, wb, (const floatx2*)(sm.prog + 16 * g), a0, a1);
                if (g + 3 < GI_G) gld_pair(gw_ih, lwb, g + 3);
            }
            sm.gi[j0]     = a0.x + a0.y;
            sm.gi[j0 + 1] = a1.x + a1.y;
        }
        // gi consumed only after later barriers

        for (int t = 0; t < NSTEPS; ++t) {
            // gh weight prefetch prologue (overlaps logits+softmax)
            gld_pair(gw_hh, lwb, 0);
            gld_pair(gw_hh, lwb, 1);
            gld_pair(gw_hh, lwb, 2);

            // attention logits: 100 dots of len 128; 4 lanes per dot
            if (tid < 4 * 2 * LL) {
                const int dot = tid >> 2;
                const int sub = tid & 3;
                const int l   = (dot < LL) ? dot : dot - LL;
                const float* p  = (dot < LL) ? (sm.h + KK) : (sm.h + 2 * KK);
                const float* kr = sm.keys + l * KP;
                float acc = 0.f;
                #pragma unroll
                for (int kk = 0; kk < KK / 4; ++kk) {
                    int k = sub + 4 * kk;
                    acc = fmaf(p[k], kr[k], acc);
                }
                acc += __shfl_xor(acc, 1, 64);
                acc += __shfl_xor(acc, 2, 64);
                if (sub == 0) {
                    if (dot < LL) sm.rl[l] = acc; else sm.wl[l] = acc;
                }
            }
            __syncthreads();

            // wave-level softmax over 50
            if (wid < 2) {
                const float* src = (wid == 0) ? sm.rl : sm.wl;
                float v = (lane < LL) ? src[lane] : -1e30f;
                float m = v;
                #pragma unroll
                for (int mm = 32; mm >= 1; mm >>= 1) m = fmaxf(m, __shfl_xor(m, mm, 64));
                float e = (lane < LL) ? __expf(v - m) : 0.f;
                float s = e;
                #pragma unroll
                for (int mm = 32; mm >= 1; mm >>= 1) s += __shfl_xor(s, mm, 64);
                if (lane < LL) {
                    float r = e * rcpf(s);
                    if (wid == 0) sm.ra[lane] = r;
                    else          sm.wmm[lane] = r;
                }
            }
            __syncthreads();

            // gh = W_hh @ h + b_hh — fp8 stream via per-wave LDS ring, no barriers
            float gh0, gh1;
            {
                floatx2 a0 = {bh2.x, 0.f}, a1 = {bh2.y, 0.f};
                #pragma unroll
                for (int g = 0; g < GH_G; ++g) {
                    if (g <= GH_G - 3)      wait_vm4();
                    else if (g == GH_G - 2) wait_vm2();
                    else                    wait_vm0();
                    const int slot = g & 3;
                    uint4 wa = *(const uint4*)(lwb + slot * 512 + lane * 4);
                    uint4 wb = *(const uint4*)(lwb + slot * 512 + 256 + lane * 4);
                    dot16(wa, wb, (const floatx2*)(sm.h + 16 * g), a0, a1);
                    if (g + 3 < GH_G) gld_pair(gw_hh, lwb, g + 3);
                }
                gh0 = a0.x + a0.y;
                gh1 = a1.x + a1.y;
            }

            // read_value + vals update — register FMAs
            if (tid < VV) {
                float rv0 = 0.f, rv1 = 0.f;
                #pragma unroll
                for (int l = 0; l < LL; l += 2) {
                    rv0 = fmaf(sm.ra[l],     vreg[l],     rv0);
                    rv1 = fmaf(sm.ra[l + 1], vreg[l + 1], rv1);
                }
                const float nv = g0 * primv + g1 * (rv0 + rv1);
                #pragma unroll
                for (int l = 0; l < LL; ++l)
                    vreg[l] = fmaf(sm.wmm[l], nv - vreg[l], vreg[l]);
            }

            *(float2*)(sm.gh + j0) = make_float2(gh0, gh1);
            __syncthreads();

            // GRU pointwise
            if (tid < HH) {
                const int j = tid;
                const float r = sigm(sm.gi[j] + sm.gh[j]);
                const float z = sigm(sm.gi[HH + j] + sm.gh[HH + j]);
                const float n = tanh_fast(sm.gi[2 * HH + j] + r * sm.gh[2 * HH + j]);
                const float hn = (1.f - z) * n + z * hcur;
                hcur = hn;
                sm.h[j] = hn;
            }
            __syncthreads();
        }
    }

    // epilogue: log-sum-exp per row (values bounded ~1 -> no max pass)
    if (tid < VV) {
        #pragma unroll
        for (int l = 0; l < LL; ++l) {
            float e = __expf(vreg[l]);
            #pragma unroll
            for (int mm = 32; mm >= 1; mm >>= 1) e += __shfl_xor(e, mm, 64);
            if (lane == 0) sm.partial[wid * LL + l] = e;
        }
    }
    __syncthreads();
    if (tid < LL) {
        float s = 0.f;
        #pragma unroll
        for (int w = 0; w < 8; ++w) s += sm.partial[w * LL + tid];
        sm.rowoff[tid] = logf(s);
    }
    __syncthreads();

    // out[b, v, l] = vreg[l] - rowoff[l]; thread v writes 50 contiguous floats
    if (tid < VV) {
        float* ob = out + (long)b * VV * LL + (long)tid * LL;
        #pragma unroll
        for (int l = 0; l < LL; l += 2) {
            float2 w2;
            w2.x = vreg[l]     - sm.rowoff[l];
            w2.y = vreg[l + 1] - sm.rowoff[l + 1];
            *(float2*)(ob + l) = w2;
        }
    }
}

__global__ void ta_copy(const int* __restrict__ ta, float* __restrict__ out2)
{
    int idx = blockIdx.x * 256 + threadIdx.x;
    if (idx < BB * LL) {
        int b2 = idx / LL, l = idx % LL;
        out2[idx] = (float)ta[l * BB + b2];
    }
}

extern "C" void kernel_launch(void* const* d_in, const int* in_sizes, int n_in,
                              void* d_out, int out_size, void* d_ws, size_t ws_size,
                              hipStream_t stream)
{
    const int*   instr        = (const int*)  d_in[0];
    const int*   true_actions = (const int*)  d_in[1];
    const float* gate_emb     = (const float*)d_in[2];
    const float* program_emb  = (const float*)d_in[3];
    const float* primitive_emb= (const float*)d_in[4];
    const float* w_ih         = (const float*)d_in[5];
    const float* w_hh         = (const float*)d_in[6];
    const float* b_ih         = (const float*)d_in[7];
    const float* b_hh         = (const float*)d_in[8];
    const float* scratch_keys = (const float*)d_in[9];
    const float* init_value   = (const float*)d_in[10];

    unsigned* wt = (unsigned*)d_ws;                 // 682 KB of ws
    const unsigned* wgh = wt;
    const unsigned* wgi = wt + WGH_U;

    {
        int total = WGH_U + WGI_U;
        pack_weights<<<(total + 255) / 256, 256, 0, stream>>>(w_hh, w_ih, wt);
    }

    float* out = (float*)d_out;
    float* out_actions = out;
    float* out_ta      = out + (long)BB * VV * LL;

    symop_main<<<BB, NT, 0, stream>>>(instr, gate_emb, program_emb, primitive_emb,
                                      wgh, wgi, b_ih, b_hh,
                                      scratch_keys, init_value, out_actions);

    ta_copy<<<(BB * LL + 255) / 256, 256, 0, stream>>>(true_actions, out_ta);
}

// Round 11
// 479.232 us; speedup vs baseline: 16.5293x; 16.5293x over previous
//
#include <hip/hip_runtime.h>
#include <math.h>

// Problem constants
#define KK     128
#define HH     384
#define H3     1152
#define PP     200
#define LL     50
#define VV     512
#define BB     256
#define II     16
#define NSTEPS 3

#define KP     129    // keys LDS pitch
#define NT     576    // 9 waves; 2*NT == H3
#define NC     256    // vals threads; thread c owns columns 2c, 2c+1

#define GHQ    24     // k-groups of 16 for w_hh (384/16)
#define PPAD   208    // prog quant range padded to 16|
#define GIQ    13     // k-groups of 16 for w_ih (208/16)
#define WQH_UI (GHQ * NT * 2 * 4)   // 110592 uints (442 KB i8)
#define WQI_UI (GIQ * NT * 2 * 4)   // 59904  uints (240 KB i8)

__device__ __forceinline__ int dot4(unsigned a, unsigned b, int c) {
    return __builtin_amdgcn_sdot4((int)a, (int)b, c, false);
}
__device__ __forceinline__ float rcpf(float x) { return __builtin_amdgcn_rcpf(x); }
__device__ __forceinline__ float sigm(float x) { return rcpf(1.f + __expf(-x)); }
__device__ __forceinline__ float tanh_fast(float x) {
    float xc = fminf(fmaxf(x, -15.f), 15.f);
    float t = __expf(2.f * xc);
    return 1.f - 2.f * rcpf(t + 1.f);
}
__device__ __forceinline__ int q8(float x, float sc) {
    int q = (int)rintf(x * sc);
    return q < -127 ? -127 : (q > 127 ? 127 : q);
}

// Pass 1: global max|w| for each weight matrix (order-independent -> deterministic)
__global__ void wmax_reduce(const float* __restrict__ w_hh,
                            const float* __restrict__ w_ih,
                            unsigned* __restrict__ scales)
{
    int idx = blockIdx.x * 256 + threadIdx.x;
    int stride = gridDim.x * 256;
    float mh = 0.f, mi = 0.f;
    for (int i = idx; i < HH * H3; i += stride) mh = fmaxf(mh, fabsf(w_hh[i]));
    for (int i = idx; i < PP * H3; i += stride) mi = fmaxf(mi, fabsf(w_ih[i]));
    #pragma unroll
    for (int mm = 32; mm >= 1; mm >>= 1) {
        mh = fmaxf(mh, __shfl_xor(mh, mm, 64));
        mi = fmaxf(mi, __shfl_xor(mi, mm, 64));
    }
    if ((threadIdx.x & 63) == 0) {
        atomicMax(scales,     __float_as_uint(mh));   // positive floats: uint-monotonic
        atomicMax(scales + 1, __float_as_uint(mi));
    }
}

// Pass 2: i8 quantized slab pack.
// uint4 index (g*NT + t)*2 + s -> row j=2t+s; uint m covers k = 16g+4m+e (byte e)
__global__ void pack_weights(const float* __restrict__ w_hh,
                             const float* __restrict__ w_ih,
                             const unsigned* __restrict__ scales,
                             unsigned* __restrict__ wq)
{
    int idx = blockIdx.x * 256 + threadIdx.x;
    if (idx < WQH_UI) {
        const float sc = 127.f * rcpf(fmaxf(__uint_as_float(scales[0]), 1e-20f));
        int u4 = idx >> 2, m = idx & 3;
        int g = u4 / (NT * 2);
        int r = u4 - g * (NT * 2);
        int t = r >> 1, s = r & 1;
        int j = 2 * t + s, k = 16 * g + 4 * m;
        const float* wr = w_hh + (long)j * HH + k;
        unsigned pw = 0;
        #pragma unroll
        for (int e = 0; e < 4; ++e) pw |= ((unsigned)(q8(wr[e], sc) & 255)) << (8 * e);
        wq[idx] = pw;
    } else if (idx < WQH_UI + WQI_UI) {
        const float sc = 127.f * rcpf(fmaxf(__uint_as_float(scales[1]), 1e-20f));
        int q = idx - WQH_UI;
        int u4 = q >> 2, m = q & 3;
        int g = u4 / (NT * 2);
        int r = u4 - g * (NT * 2);
        int t = r >> 1, s = r & 1;
        int j = 2 * t + s, k = 16 * g + 4 * m;
        unsigned pw = 0;
        #pragma unroll
        for (int e = 0; e < 4; ++e) {
            float w = (k + e < PP) ? w_ih[(long)j * PP + k + e] : 0.f;
            pw |= ((unsigned)(q8(w, sc) & 255)) << (8 * e);
        }
        wq[WQH_UI + (q - 0)] = pw;
    }
}

struct __align__(16) Smem {
    float2 vals[LL * NC];                                    // 100 KB
    float  keys[LL * KP];
    float  h[HH]         __attribute__((aligned(16)));       // f32 h (logits)
    unsigned hq[HH / 4]  __attribute__((aligned(16)));       // i8 h (GEMV)
    float  prog[256]     __attribute__((aligned(16)));       // zero-padded
    unsigned progq[PPAD / 4] __attribute__((aligned(16)));   // i8 prog
    float  gi[H3]        __attribute__((aligned(16)));
    float  gh[H3]        __attribute__((aligned(16)));
    float  ra[LL], wmm[LL], rl[LL], wl[LL], rowoff[LL];
    float  partial[4 * LL];
    float  pscale;
};  // ~139 KB

__global__ __launch_bounds__(NT)
void symop_main(const int* __restrict__ instr,
                const float* __restrict__ gate_emb,
                const float* __restrict__ program_emb,
                const float* __restrict__ primitive_emb,
                const uint4* __restrict__ wqhh,
                const uint4* __restrict__ wqih,
                const unsigned* __restrict__ scales,
                const float* __restrict__ b_ih,
                const float* __restrict__ b_hh,
                const float* __restrict__ keys_g,
                const float* __restrict__ init_value,
                float* __restrict__ out)
{
    __shared__ Smem sm;

    const int tid  = threadIdx.x;
    const int lane = tid & 63;
    const int wid  = tid >> 6;
    const int b    = blockIdx.x;

    const float ghs      = fmaxf(__uint_as_float(scales[0]), 1e-20f) * (1.f / 16129.f);
    const float gis_base = fmaxf(__uint_as_float(scales[1]), 1e-20f) * (1.f / 16129.f);

    // init
    for (int idx = tid; idx < LL * KK; idx += NT) {
        int l = idx >> 7, k = idx & 127;
        sm.keys[l * KP + k] = keys_g[idx];
    }
    float hcur = 0.f;
    if (tid < HH) {
        hcur = keys_g[tid & 127];
        sm.h[tid] = hcur;
    }
    if (tid < HH / 4) {
        unsigned pw = 0;
        #pragma unroll
        for (int e = 0; e < 4; ++e) {
            int q = (int)rintf(keys_g[(4 * tid + e) & 127] * 127.f);
            pw |= ((unsigned)(q & 255)) << (8 * e);
        }
        sm.hq[tid] = pw;
    }
    if (tid < NC) {
        float2 iv = *(const float2*)(init_value + 2 * tid);
        for (int l = 0; l < LL; ++l) sm.vals[l * NC + tid] = iv;
    }
    __syncthreads();

    const int j0 = 2 * tid;
    const float2 bh2 = *(const float2*)(b_hh + j0);
    const float2 bi2 = *(const float2*)(b_ih + j0);

    for (int i = 0; i < II; ++i) {
        const int word = instr[i * BB + b];
        const float ge0 = gate_emb[2 * word], ge1 = gate_emb[2 * word + 1];
        const float gmx = fmaxf(ge0, ge1);
        const float e0 = __expf(ge0 - gmx), e1 = __expf(ge1 - gmx);
        const float g0 = e0 * rcpf(e0 + e1), g1 = 1.0f - g0;
        float2 prim2 = make_float2(0.f, 0.f);
        if (tid < NC) prim2 = *(const float2*)(primitive_emb + (long)word * VV + 2 * tid);
        const float* pge = program_emb + (long)word * PP;

        if (tid < 256) sm.prog[tid] = (tid < PP) ? pge[tid] : 0.f;
        __syncthreads();

        // per-word prog max (wave 0)
        if (wid == 0) {
            float v = fmaxf(fmaxf(fabsf(sm.prog[lane]),       fabsf(sm.prog[lane + 64])),
                            fmaxf(fabsf(sm.prog[lane + 128]), fabsf(sm.prog[lane + 192])));
            #pragma unroll
            for (int mm = 32; mm >= 1; mm >>= 1) v = fmaxf(v, __shfl_xor(v, mm, 64));
            if (lane == 0) sm.pscale = fmaxf(v, 1e-20f);
        }
        __syncthreads();

        // quantize prog to i8
        if (tid < PPAD / 4) {
            const float sc = 127.f * rcpf(sm.pscale);
            const float* p = sm.prog + 4 * tid;
            unsigned pw = 0;
            #pragma unroll
            for (int e = 0; e < 4; ++e) pw |= ((unsigned)(q8(p[e], sc) & 255)) << (8 * e);
            sm.progq[tid] = pw;
        }
        __syncthreads();

        // gi = W_ih @ prog + b_ih  (i8 dot4)
        {
            int ia0 = 0, ia1 = 0;
            const uint4* wp = wqih + (size_t)tid * 2;
            #pragma unroll 4
            for (int g = 0; g < GIQ; ++g) {
                uint4 wa = wp[(size_t)g * (NT * 2)];
                uint4 wb = wp[(size_t)g * (NT * 2) + 1];
                uint4 hp = *(const uint4*)(sm.progq + 4 * g);
                ia0 = dot4(wa.x, hp.x, ia0); ia0 = dot4(wa.y, hp.y, ia0);
                ia0 = dot4(wa.z, hp.z, ia0); ia0 = dot4(wa.w, hp.w, ia0);
                ia1 = dot4(wb.x, hp.x, ia1); ia1 = dot4(wb.y, hp.y, ia1);
                ia1 = dot4(wb.z, hp.z, ia1); ia1 = dot4(wb.w, hp.w, ia1);
            }
            const float gis = gis_base * sm.pscale;
            sm.gi[j0]     = bi2.x + (float)ia0 * gis;
            sm.gi[j0 + 1] = bi2.y + (float)ia1 * gis;
        }
        // gi consumed only after later barriers

        for (int t = 0; t < NSTEPS; ++t) {
            // Phase A: attention logits (100 dots of 128; 4 lanes/dot)
            if (tid < 4 * 2 * LL) {
                const int dot = tid >> 2;
                const int sub = tid & 3;
                const int l   = (dot < LL) ? dot : dot - LL;
                const float* p  = (dot < LL) ? (sm.h + KK) : (sm.h + 2 * KK);
                const float* kr = sm.keys + l * KP;
                float acc = 0.f;
                #pragma unroll
                for (int kk = 0; kk < KK / 4; ++kk) {
                    int k = sub + 4 * kk;
                    acc = fmaf(p[k], kr[k], acc);
                }
                acc += __shfl_xor(acc, 1, 64);
                acc += __shfl_xor(acc, 2, 64);
                if (sub == 0) {
                    if (dot < LL) sm.rl[l] = acc; else sm.wl[l] = acc;
                }
            }
            __syncthreads();

            // Phase B: softmax (waves 0-1) overlapped with gh i8 GEMV (all waves)
            if (wid < 2) {
                const float* src = (wid == 0) ? sm.rl : sm.wl;
                float v = (lane < LL) ? src[lane] : -1e30f;
                float m = v;
                #pragma unroll
                for (int mm = 32; mm >= 1; mm >>= 1) m = fmaxf(m, __shfl_xor(m, mm, 64));
                float e = (lane < LL) ? __expf(v - m) : 0.f;
                float s = e;
                #pragma unroll
                for (int mm = 32; mm >= 1; mm >>= 1) s += __shfl_xor(s, mm, 64);
                if (lane < LL) {
                    float r = e * rcpf(s);
                    if (wid == 0) sm.ra[lane] = r;
                    else          sm.wmm[lane] = r;
                }
            }
            {
                int ia0 = 0, ia1 = 0;
                const uint4* wp = wqhh + (size_t)tid * 2;
                #pragma unroll 4
                for (int g = 0; g < GHQ; ++g) {
                    uint4 wa = wp[(size_t)g * (NT * 2)];
                    uint4 wb = wp[(size_t)g * (NT * 2) + 1];
                    uint4 hp = *(const uint4*)(sm.hq + 4 * g);
                    ia0 = dot4(wa.x, hp.x, ia0); ia0 = dot4(wa.y, hp.y, ia0);
                    ia0 = dot4(wa.z, hp.z, ia0); ia0 = dot4(wa.w, hp.w, ia0);
                    ia1 = dot4(wb.x, hp.x, ia1); ia1 = dot4(wb.y, hp.y, ia1);
                    ia1 = dot4(wb.z, hp.z, ia1); ia1 = dot4(wb.w, hp.w, ia1);
                }
                *(float2*)(sm.gh + j0) = make_float2(bh2.x + (float)ia0 * ghs,
                                                     bh2.y + (float)ia1 * ghs);
            }
            __syncthreads();

            // Phase C: vals update (LDS, waves 0-3) + GRU (waves 0-5)
            if (tid < NC) {
                float rv0 = 0.f, rv1 = 0.f;
                #pragma unroll 10
                for (int l = 0; l < LL; ++l) {
                    float2 vv = sm.vals[l * NC + tid];
                    rv0 = fmaf(sm.ra[l], vv.x, rv0);
                    rv1 = fmaf(sm.ra[l], vv.y, rv1);
                }
                const float nv0 = g0 * prim2.x + g1 * rv0;
                const float nv1 = g0 * prim2.y + g1 * rv1;
                #pragma unroll 10
                for (int l = 0; l < LL; ++l) {
                    float2 vv = sm.vals[l * NC + tid];
                    const float w = sm.wmm[l];
                    vv.x = fmaf(w, nv0 - vv.x, vv.x);
                    vv.y = fmaf(w, nv1 - vv.y, vv.y);
                    sm.vals[l * NC + tid] = vv;
                }
            }
            if (tid < HH) {
                const int j = tid;
                const float r = sigm(sm.gi[j] + sm.gh[j]);
                const float z = sigm(sm.gi[HH + j] + sm.gh[HH + j]);
                const float n = tanh_fast(sm.gi[2 * HH + j] + r * sm.gh[2 * HH + j]);
                const float hn = (1.f - z) * n + z * hcur;   // |hn| <= 1 by induction
                hcur = hn;
                sm.h[j] = hn;
                int q = (int)rintf(hn * 127.f);
                int q1 = __shfl_down(q, 1, 64);
                int q2 = __shfl_down(q, 2, 64);
                int q3 = __shfl_down(q, 3, 64);
                if (!(tid & 3))
                    sm.hq[tid >> 2] = (unsigned)((q & 255) | ((q1 & 255) << 8) |
                                                 ((q2 & 255) << 16) | ((q3 & 255) << 24));
            }
            __syncthreads();
        }
    }

    // epilogue: log-sum-exp per row (values bounded ~1 -> no max pass)
    if (tid < NC) {
        #pragma unroll 5
        for (int l = 0; l < LL; ++l) {
            float2 vv = sm.vals[l * NC + tid];
            float e = __expf(vv.x) + __expf(vv.y);
            #pragma unroll
            for (int mm = 32; mm >= 1; mm >>= 1) e += __shfl_xor(e, mm, 64);
            if (lane == 0) sm.partial[wid * LL + l] = e;
        }
    }
    __syncthreads();
    if (tid < LL) {
        float s = 0.f;
        #pragma unroll
        for (int w = 0; w < 4; ++w) s += sm.partial[w * LL + tid];
        sm.rowoff[tid] = logf(s);
    }
    __syncthreads();

    if (tid < NC) {
        float* ob0 = out + (long)b * VV * LL + (long)(2 * tid) * LL;
        float* ob1 = ob0 + LL;
        #pragma unroll 5
        for (int l = 0; l < LL; l += 2) {
            float2 va = sm.vals[l * NC + tid];
            float2 vb = sm.vals[(l + 1) * NC + tid];
            float o0 = sm.rowoff[l], o1 = sm.rowoff[l + 1];
            *(float2*)(ob0 + l) = make_float2(va.x - o0, vb.x - o1);
            *(float2*)(ob1 + l) = make_float2(va.y - o0, vb.y - o1);
        }
    }
}

__global__ void ta_copy(const int* __restrict__ ta, float* __restrict__ out2)
{
    int idx = blockIdx.x * 256 + threadIdx.x;
    if (idx < BB * LL) {
        int b2 = idx / LL, l = idx % LL;
        out2[idx] = (float)ta[l * BB + b2];
    }
}

extern "C" void kernel_launch(void* const* d_in, const int* in_sizes, int n_in,
                              void* d_out, int out_size, void* d_ws, size_t ws_size,
                              hipStream_t stream)
{
    const int*   instr        = (const int*)  d_in[0];
    const int*   true_actions = (const int*)  d_in[1];
    const float* gate_emb     = (const float*)d_in[2];
    const float* program_emb  = (const float*)d_in[3];
    const float* primitive_emb= (const float*)d_in[4];
    const float* w_ih         = (const float*)d_in[5];
    const float* w_hh         = (const float*)d_in[6];
    const float* b_ih         = (const float*)d_in[7];
    const float* b_hh         = (const float*)d_in[8];
    const float* scratch_keys = (const float*)d_in[9];
    const float* init_value   = (const float*)d_in[10];

    unsigned* scales = (unsigned*)d_ws;               // [0]=max|w_hh| [1]=max|w_ih|
    unsigned* wq     = (unsigned*)d_ws + 4;           // 16B-aligned weight slabs
    const uint4* wqhh = (const uint4*)wq;
    const uint4* wqih = (const uint4*)(wq + WQH_UI);

    hipMemsetAsync(scales, 0, 8, stream);
    wmax_reduce<<<256, 256, 0, stream>>>(w_hh, w_ih, scales);
    {
        int total = WQH_UI + WQI_UI;
        pack_weights<<<(total + 255) / 256, 256, 0, stream>>>(w_hh, w_ih, scales, wq);
    }

    float* out = (float*)d_out;
    float* out_actions = out;
    float* out_ta      = out + (long)BB * VV * LL;

    symop_main<<<BB, NT, 0, stream>>>(instr, gate_emb, program_emb, primitive_emb,
                                      wqhh, wqih, scales, b_ih, b_hh,
                                      scratch_keys, init_value, out_actions);

    ta_copy<<<(BB * LL + 255) / 256, 256, 0, stream>>>(true_actions, out_ta);
}

// Round 12
// 416.601 us; speedup vs baseline: 19.0142x; 1.1503x over previous
//
#include <hip/hip_runtime.h>
#include <math.h>

// Problem constants
#define KK     128
#define HH     384
#define H3     1152
#define PP     200
#define LL     50
#define VV     512
#define BB     256
#define II     16
#define NSTEPS 3

#define NT     576     // 9 waves
#define KPW    132     // keys pitch: bank=(4l+sub)%32 -> conflict-free logits
#define VP2    258     // vals float2 pitch

#define GHG    24      // k-groups of 16 for w_hh (384/16)
#define GIG    13      // k-groups of 16 for w_ih (208/16, zero-padded)
#define GH_U4  (GHG * 3 * 384)    // 27648 uint4
#define GI_U4  (GIG * 3 * 384)    // 14976 uint4
#define WQH_UI (GH_U4 * 4)        // 110592 uints (442 KB)
#define WQI_UI (GI_U4 * 4)        // 59904  uints (240 KB)

__device__ __forceinline__ int dot4(unsigned a, unsigned b, int c) {
    return __builtin_amdgcn_sdot4((int)a, (int)b, c, false);
}
__device__ __forceinline__ float rcpf(float x) { return __builtin_amdgcn_rcpf(x); }
__device__ __forceinline__ float sigm(float x) { return rcpf(1.f + __expf(-x)); }
__device__ __forceinline__ float tanh_fast(float x) {
    float xc = fminf(fmaxf(x, -15.f), 15.f);
    float t = __expf(2.f * xc);
    return 1.f - 2.f * rcpf(t + 1.f);
}
__device__ __forceinline__ int q8(float x, float sc) {
    int q = (int)rintf(x * sc);
    return q < -127 ? -127 : (q > 127 ? 127 : q);
}

// Pass 1: global max|.| for w_hh, w_ih, program_emb (order-independent)
__global__ void wmax_reduce(const float* __restrict__ w_hh,
                            const float* __restrict__ w_ih,
                            const float* __restrict__ prog_emb,
                            unsigned* __restrict__ scales)
{
    int idx = blockIdx.x * 256 + threadIdx.x;
    int stride = gridDim.x * 256;
    float mh = 0.f, mi = 0.f, mp = 0.f;
    for (int i = idx; i < HH * H3; i += stride) mh = fmaxf(mh, fabsf(w_hh[i]));
    for (int i = idx; i < PP * H3; i += stride) mi = fmaxf(mi, fabsf(w_ih[i]));
    for (int i = idx; i < 1000 * PP; i += stride) mp = fmaxf(mp, fabsf(prog_emb[i]));
    #pragma unroll
    for (int mm = 32; mm >= 1; mm >>= 1) {
        mh = fmaxf(mh, __shfl_xor(mh, mm, 64));
        mi = fmaxf(mi, __shfl_xor(mi, mm, 64));
        mp = fmaxf(mp, __shfl_xor(mp, mm, 64));
    }
    if ((threadIdx.x & 63) == 0) {
        atomicMax(scales,     __float_as_uint(mh));
        atomicMax(scales + 1, __float_as_uint(mi));
        atomicMax(scales + 2, __float_as_uint(mp));
    }
}

// Pass 2: i8 slab pack. uint4 index (g*3 + s)*384 + t -> row j = t + 384*s,
// uint m covers k = 16g + 4m + e (byte e). GH block first, then GI.
__global__ void pack_weights(const float* __restrict__ w_hh,
                             const float* __restrict__ w_ih,
                             const unsigned* __restrict__ scales,
                             unsigned* __restrict__ wq)
{
    int idx = blockIdx.x * 256 + threadIdx.x;
    if (idx < WQH_UI) {
        const float sc = 127.f * rcpf(fmaxf(__uint_as_float(scales[0]), 1e-20f));
        int u4 = idx >> 2, m = idx & 3;
        int g = u4 / (3 * 384);
        int r = u4 - g * (3 * 384);
        int s = r / 384, t = r - s * 384;
        int j = t + 384 * s, k = 16 * g + 4 * m;
        const float* wr = w_hh + (long)j * HH + k;
        unsigned pw = 0;
        #pragma unroll
        for (int e = 0; e < 4; ++e) pw |= ((unsigned)(q8(wr[e], sc) & 255)) << (8 * e);
        wq[idx] = pw;
    } else if (idx < WQH_UI + WQI_UI) {
        const float sc = 127.f * rcpf(fmaxf(__uint_as_float(scales[1]), 1e-20f));
        int q = idx - WQH_UI;
        int u4 = q >> 2, m = q & 3;
        int g = u4 / (3 * 384);
        int r = u4 - g * (3 * 384);
        int s = r / 384, t = r - s * 384;
        int j = t + 384 * s, k = 16 * g + 4 * m;
        unsigned pw = 0;
        #pragma unroll
        for (int e = 0; e < 4; ++e) {
            float w = (k + e < PP) ? w_ih[(long)j * PP + k + e] : 0.f;
            pw |= ((unsigned)(q8(w, sc) & 255)) << (8 * e);
        }
        wq[WQH_UI + u4 * 4 + m] = pw;
    }
}

struct __align__(16) Smem {
    float2 vals[LL * VP2];                                   // 103 KB
    float  keys[LL * KPW];                                   // 26.4 KB
    float  h[HH]            __attribute__((aligned(16)));
    unsigned hq[HH / 4]     __attribute__((aligned(16)));
    unsigned progq[56]      __attribute__((aligned(16)));
    float  rl[52], wl[52];
    float  raw[3][52], wmw[3][52];   // per-wave softmax scratch (waves 6-8)
    float  rowoff[52];
    float  partial[4 * 52];
};  // ~135 KB

__global__ __launch_bounds__(NT)
void symop_main(const int* __restrict__ instr,
                const float* __restrict__ gate_emb,
                const float* __restrict__ program_emb,
                const float* __restrict__ primitive_emb,
                const uint4* __restrict__ wqhh,
                const uint4* __restrict__ wqih,
                const unsigned* __restrict__ scales,
                const float* __restrict__ b_ih,
                const float* __restrict__ b_hh,
                const float* __restrict__ keys_g,
                const float* __restrict__ init_value,
                float* __restrict__ out)
{
    __shared__ Smem sm;

    const int tid  = threadIdx.x;
    const int lane = tid & 63;
    const int wid  = tid >> 6;
    const int b    = blockIdx.x;

    const float maxH = fmaxf(__uint_as_float(scales[0]), 1e-20f);
    const float maxI = fmaxf(__uint_as_float(scales[1]), 1e-20f);
    const float maxP = fmaxf(__uint_as_float(scales[2]), 1e-20f);
    const float ghs = maxH * (1.f / 16129.f);
    const float gis = maxI * maxP * (1.f / 16129.f);
    const float psc = 127.f * rcpf(maxP);

    // ---- init ----
    for (int idx = tid; idx < LL * KK; idx += NT) {
        int l = idx >> 7, k = idx & 127;
        sm.keys[l * KPW + k] = keys_g[idx];
    }
    float hcur = 0.f;
    if (tid < HH) {
        hcur = keys_g[tid & 127];
        sm.h[tid] = hcur;
    }
    if (tid < HH / 4) {
        unsigned pw = 0;
        #pragma unroll
        for (int e = 0; e < 4; ++e) {
            int q = (int)rintf(keys_g[(4 * tid + e) & 127] * 127.f);
            pw |= ((unsigned)(q & 255)) << (8 * e);
        }
        sm.hq[tid] = pw;
    }
    for (int idx = tid; idx < LL * 256; idx += NT) {
        int l = idx >> 8, c = idx & 255;
        sm.vals[l * VP2 + c] = *(const float2*)(init_value + 2 * c);
    }
    if (tid >= 448 && tid < 448 + 52) {       // stage progq for word 0
        int qt = tid - 448;
        int w0 = instr[b];
        const float* pg = program_emb + (long)w0 * PP;
        unsigned pw = 0;
        #pragma unroll
        for (int e = 0; e < 4; ++e) {
            int k = 4 * qt + e;
            float v = (k < PP) ? pg[k] : 0.f;
            pw |= ((unsigned)(q8(v, psc) & 255)) << (8 * e);
        }
        sm.progq[qt] = pw;
    }
    __syncthreads();

    // biases (thread tid owns GRU lane tid: rows tid, tid+384, tid+768)
    float bh0 = 0, bh1 = 0, bh2 = 0, bi0 = 0, bi1 = 0, bi2 = 0;
    if (tid < HH) {
        bh0 = b_hh[tid]; bh1 = b_hh[tid + HH]; bh2 = b_hh[tid + 2 * HH];
        bi0 = b_ih[tid]; bi1 = b_ih[tid + HH]; bi2 = b_ih[tid + 2 * HH];
    }
    float gic0 = 0, gic1 = 0, gic2 = 0;   // current word's gi rows (registers)

    // ---- prologue: gi word0 (waves 0-5) || logits step0 (threads 384-483) ----
    if (tid < HH) {
        int ia0 = 0, ia1 = 0, ia2 = 0;
        const uint4* wp = wqih + tid;
        #pragma unroll 2
        for (int g = 0; g < GIG; ++g) {
            uint4 w0 = wp[(g * 3 + 0) * 384];
            uint4 w1 = wp[(g * 3 + 1) * 384];
            uint4 w2 = wp[(g * 3 + 2) * 384];
            uint4 hp = *(const uint4*)(sm.progq + 4 * g);
            ia0 = dot4(w0.x, hp.x, ia0); ia0 = dot4(w0.y, hp.y, ia0);
            ia0 = dot4(w0.z, hp.z, ia0); ia0 = dot4(w0.w, hp.w, ia0);
            ia1 = dot4(w1.x, hp.x, ia1); ia1 = dot4(w1.y, hp.y, ia1);
            ia1 = dot4(w1.z, hp.z, ia1); ia1 = dot4(w1.w, hp.w, ia1);
            ia2 = dot4(w2.x, hp.x, ia2); ia2 = dot4(w2.y, hp.y, ia2);
            ia2 = dot4(w2.z, hp.z, ia2); ia2 = dot4(w2.w, hp.w, ia2);
        }
        gic0 = bi0 + (float)ia0 * gis;
        gic1 = bi1 + (float)ia1 * gis;
        gic2 = bi2 + (float)ia2 * gis;
    } else if (tid < HH + 2 * LL) {           // 100 threads, one dot each
        int dd = tid - HH;
        int l = (dd < LL) ? dd : dd - LL;
        const float* p  = (dd < LL) ? (sm.h + KK) : (sm.h + 2 * KK);
        const float* kr = sm.keys + l * KPW;
        float acc = 0.f;
        #pragma unroll 8
        for (int k = 0; k < KK; ++k) acc = fmaf(p[k], kr[k], acc);
        if (dd < LL) sm.rl[l] = acc; else sm.wl[l] = acc;
    }
    __syncthreads();

    for (int i = 0; i < II; ++i) {
        const int word = instr[i * BB + b];
        for (int t = 0; t < NSTEPS; ++t) {
            // ================= P2: gh+GRU (waves 0-5) || softmax+vals (waves 6-8)
            if (tid < HH) {
                int ia0 = 0, ia1 = 0, ia2 = 0;
                const uint4* wp = wqhh + tid;
                #pragma unroll 2
                for (int g = 0; g < GHG; ++g) {
                    uint4 w0 = wp[(g * 3 + 0) * 384];
                    uint4 w1 = wp[(g * 3 + 1) * 384];
                    uint4 w2 = wp[(g * 3 + 2) * 384];
                    uint4 hp = *(const uint4*)(sm.hq + 4 * g);
                    ia0 = dot4(w0.x, hp.x, ia0); ia0 = dot4(w0.y, hp.y, ia0);
                    ia0 = dot4(w0.z, hp.z, ia0); ia0 = dot4(w0.w, hp.w, ia0);
                    ia1 = dot4(w1.x, hp.x, ia1); ia1 = dot4(w1.y, hp.y, ia1);
                    ia1 = dot4(w1.z, hp.z, ia1); ia1 = dot4(w1.w, hp.w, ia1);
                    ia2 = dot4(w2.x, hp.x, ia2); ia2 = dot4(w2.y, hp.y, ia2);
                    ia2 = dot4(w2.z, hp.z, ia2); ia2 = dot4(w2.w, hp.w, ia2);
                }
                const float gh0 = bh0 + (float)ia0 * ghs;
                const float gh1 = bh1 + (float)ia1 * ghs;
                const float gh2 = bh2 + (float)ia2 * ghs;

                // stage next word's gi (progq staged in previous P1)
                float gn0 = gic0, gn1 = gic1, gn2 = gic2;
                if (t == 2 && i + 1 < II) {
                    int ib0 = 0, ib1 = 0, ib2 = 0;
                    const uint4* wi = wqih + tid;
                    #pragma unroll 2
                    for (int g = 0; g < GIG; ++g) {
                        uint4 w0 = wi[(g * 3 + 0) * 384];
                        uint4 w1 = wi[(g * 3 + 1) * 384];
                        uint4 w2 = wi[(g * 3 + 2) * 384];
                        uint4 hp = *(const uint4*)(sm.progq + 4 * g);
                        ib0 = dot4(w0.x, hp.x, ib0); ib0 = dot4(w0.y, hp.y, ib0);
                        ib0 = dot4(w0.z, hp.z, ib0); ib0 = dot4(w0.w, hp.w, ib0);
                        ib1 = dot4(w1.x, hp.x, ib1); ib1 = dot4(w1.y, hp.y, ib1);
                        ib1 = dot4(w1.z, hp.z, ib1); ib1 = dot4(w1.w, hp.w, ib1);
                        ib2 = dot4(w2.x, hp.x, ib2); ib2 = dot4(w2.y, hp.y, ib2);
                        ib2 = dot4(w2.z, hp.z, ib2); ib2 = dot4(w2.w, hp.w, ib2);
                    }
                    gn0 = bi0 + (float)ib0 * gis;
                    gn1 = bi1 + (float)ib1 * gis;
                    gn2 = bi2 + (float)ib2 * gis;
                }

                // GRU (register-local: this thread owns rows tid, tid+384, tid+768)
                const float r = sigm(gic0 + gh0);
                const float z = sigm(gic1 + gh1);
                const float n = tanh_fast(gic2 + r * gh2);
                const float hn = (1.f - z) * n + z * hcur;   // |hn| <= 1
                hcur = hn;
                sm.h[tid] = hn;
                int q = (int)rintf(hn * 127.f);
                int q1 = __shfl_down(q, 1, 64);
                int q2 = __shfl_down(q, 2, 64);
                int q3 = __shfl_down(q, 3, 64);
                if (!(tid & 3))
                    sm.hq[tid >> 2] = (unsigned)((q & 255) | ((q1 & 255) << 8) |
                                                 ((q2 & 255) << 16) | ((q3 & 255) << 24));
                gic0 = gn0; gic1 = gn1; gic2 = gn2;
            } else {
                // redundant per-wave softmax (no cross-wave dependency)
                const int w3 = wid - 6;
                float vr = (lane < LL) ? sm.rl[lane] : -1e30f;
                float mr = vr;
                #pragma unroll
                for (int mm = 32; mm >= 1; mm >>= 1) mr = fmaxf(mr, __shfl_xor(mr, mm, 64));
                float er = (lane < LL) ? __expf(vr - mr) : 0.f;
                float sr = er;
                #pragma unroll
                for (int mm = 32; mm >= 1; mm >>= 1) sr += __shfl_xor(sr, mm, 64);
                float vw = (lane < LL) ? sm.wl[lane] : -1e30f;
                float mw = vw;
                #pragma unroll
                for (int mm = 32; mm >= 1; mm >>= 1) mw = fmaxf(mw, __shfl_xor(mw, mm, 64));
                float ew = (lane < LL) ? __expf(vw - mw) : 0.f;
                float sw = ew;
                #pragma unroll
                for (int mm = 32; mm >= 1; mm >>= 1) sw += __shfl_xor(sw, mm, 64);
                if (lane < LL) {
                    sm.raw[w3][lane] = er * rcpf(sr);
                    sm.wmw[w3][lane] = ew * rcpf(sw);
                }
                // gate
                const float ge0 = gate_emb[2 * word], ge1 = gate_emb[2 * word + 1];
                const float gmx = fmaxf(ge0, ge1);
                const float e0 = __expf(ge0 - gmx), e1 = __expf(ge1 - gmx);
                const float g0 = e0 * rcpf(e0 + e1), g1 = 1.0f - g0;
                const float* prim = primitive_emb + (long)word * VV;

                const int vt = tid - HH;   // 0..191
                for (int c = vt; c < 256; c += 192) {
                    float2 pr = *(const float2*)(prim + 2 * c);
                    float rv0 = 0.f, rv1 = 0.f;
                    #pragma unroll 10
                    for (int l = 0; l < LL; ++l) {
                        float2 vv = sm.vals[l * VP2 + c];
                        rv0 = fmaf(sm.raw[w3][l], vv.x, rv0);
                        rv1 = fmaf(sm.raw[w3][l], vv.y, rv1);
                    }
                    const float nv0 = g0 * pr.x + g1 * rv0;
                    const float nv1 = g0 * pr.y + g1 * rv1;
                    #pragma unroll 10
                    for (int l = 0; l < LL; ++l) {
                        float2 vv = sm.vals[l * VP2 + c];
                        const float w = sm.wmw[w3][l];
                        vv.x = fmaf(w, nv0 - vv.x, vv.x);
                        vv.y = fmaf(w, nv1 - vv.y, vv.y);
                        sm.vals[l * VP2 + c] = vv;
                    }
                }
            }
            __syncthreads();

            // ================= P1: logits for next step (+ prog staging at t==2)
            if (tid < 4 * 2 * LL) {
                const int dot = tid >> 2;
                const int sub = tid & 3;
                const int l   = (dot < LL) ? dot : dot - LL;
                const float* p  = (dot < LL) ? (sm.h + KK) : (sm.h + 2 * KK);
                const float* kr = sm.keys + l * KPW;
                float acc = 0.f;
                #pragma unroll
                for (int kk = 0; kk < KK / 4; ++kk) {
                    int k = sub + 4 * kk;
                    acc = fmaf(p[k], kr[k], acc);
                }
                acc += __shfl_xor(acc, 1, 64);
                acc += __shfl_xor(acc, 2, 64);
                if (sub == 0) {
                    if (dot < LL) sm.rl[l] = acc; else sm.wl[l] = acc;
                }
            } else if (t == 2 && i + 1 < II && tid >= 448 && tid < 448 + 52) {
                int qt = tid - 448;
                int wn = instr[(i + 1) * BB + b];
                const float* pg = program_emb + (long)wn * PP;
                unsigned pw = 0;
                #pragma unroll
                for (int e = 0; e < 4; ++e) {
                    int k = 4 * qt + e;
                    float v = (k < PP) ? pg[k] : 0.f;
                    pw |= ((unsigned)(q8(v, psc) & 255)) << (8 * e);
                }
                sm.progq[qt] = pw;
            }
            __syncthreads();
        }
    }

    // ---- epilogue: log-sum-exp per row (values bounded ~1 -> no max pass) ----
    if (tid < 256) {
        #pragma unroll 5
        for (int l = 0; l < LL; ++l) {
            float2 vv = sm.vals[l * VP2 + tid];
            float e = __expf(vv.x) + __expf(vv.y);
            #pragma unroll
            for (int mm = 32; mm >= 1; mm >>= 1) e += __shfl_xor(e, mm, 64);
            if (lane == 0) sm.partial[wid * 52 + l] = e;
        }
    }
    __syncthreads();
    if (tid < LL) {
        float s = 0.f;
        #pragma unroll
        for (int w = 0; w < 4; ++w) s += sm.partial[w * 52 + tid];
        sm.rowoff[tid] = logf(s);
    }
    __syncthreads();

    if (tid < 256) {
        float* ob0 = out + (long)b * VV * LL + (long)(2 * tid) * LL;
        float* ob1 = ob0 + LL;
        #pragma unroll 5
        for (int l = 0; l < LL; l += 2) {
            float2 va = sm.vals[l * VP2 + tid];
            float2 vb = sm.vals[(l + 1) * VP2 + tid];
            float o0 = sm.rowoff[l], o1 = sm.rowoff[l + 1];
            *(float2*)(ob0 + l) = make_float2(va.x - o0, vb.x - o1);
            *(float2*)(ob1 + l) = make_float2(va.y - o0, vb.y - o1);
        }
    }
}

__global__ void ta_copy(const int* __restrict__ ta, float* __restrict__ out2)
{
    int idx = blockIdx.x * 256 + threadIdx.x;
    if (idx < BB * LL) {
        int b2 = idx / LL, l = idx % LL;
        out2[idx] = (float)ta[l * BB + b2];
    }
}

extern "C" void kernel_launch(void* const* d_in, const int* in_sizes, int n_in,
                              void* d_out, int out_size, void* d_ws, size_t ws_size,
                              hipStream_t stream)
{
    const int*   instr        = (const int*)  d_in[0];
    const int*   true_actions = (const int*)  d_in[1];
    const float* gate_emb     = (const float*)d_in[2];
    const float* program_emb  = (const float*)d_in[3];
    const float* primitive_emb= (const float*)d_in[4];
    const float* w_ih         = (const float*)d_in[5];
    const float* w_hh         = (const float*)d_in[6];
    const float* b_ih         = (const float*)d_in[7];
    const float* b_hh         = (const float*)d_in[8];
    const float* scratch_keys = (const float*)d_in[9];
    const float* init_value   = (const float*)d_in[10];

    unsigned* scales = (unsigned*)d_ws;            // [0..2] maxima
    unsigned* wq     = (unsigned*)d_ws + 4;        // 16B-aligned slabs
    const uint4* wqhh = (const uint4*)wq;
    const uint4* wqih = (const uint4*)(wq + WQH_UI);

    hipMemsetAsync(scales, 0, 12, stream);
    wmax_reduce<<<256, 256, 0, stream>>>(w_hh, w_ih, program_emb, scales);
    {
        int total = WQH_UI + WQI_UI;
        pack_weights<<<(total + 255) / 256, 256, 0, stream>>>(w_hh, w_ih, scales, wq);
    }

    float* out = (float*)d_out;
    float* out_actions = out;
    float* out_ta      = out + (long)BB * VV * LL;

    symop_main<<<BB, NT, 0, stream>>>(instr, gate_emb, program_emb, primitive_emb,
                                      wqhh, wqih, scales, b_ih, b_hh,
                                      scratch_keys, init_value, out_actions);

    ta_copy<<<(BB * LL + 255) / 256, 256, 0, stream>>>(true_actions, out_ta);
}